// Round 2
// baseline (1141.376 us; speedup 1.0000x reference)
//
#include <hip/hip_runtime.h>
#include <hip/hip_bf16.h>

#define B_ 8
#define C_ 256
#define H_ 128
#define W_ 128
#define HW_ 16384
#define CHW_ (C_ * HW_)
#define NH_ 8
#define HD_ 32
#define NTOT (B_ * CHW_)   // 33,554,432

// ---------------- FUSED depthwise 3x3 conv + offset projection + tanh ----------------
// Grid: 8 batches x 64 tiles (16x16 px). 256 threads = one per pixel.
// Loop channels in chunks of 4; stage 18x18 halo tiles in LDS; accumulate the
// 16-wide offset projection in registers. hdw (134 MB) never hits HBM.
__global__ __launch_bounds__(256) void fused_offset_kernel(const float* __restrict__ x,
                                                           const float* __restrict__ dww,
                                                           const float* __restrict__ offw,
                                                           const float* __restrict__ offb,
                                                           float* __restrict__ offout) {
    __shared__ float xt[4][18][20];     // 4 channels, 18x18 halo tile, pad to 20
    __shared__ float wT[256][16];       // offset weights [c][o], 16 KB
    __shared__ float wd[256][9];        // dw weights, 9 KB
    __shared__ float bsh[16];

    const int tid = threadIdx.x;
    const int bx = blockIdx.x;
    const int b = bx >> 6;
    const int tile = bx & 63;
    const int h0 = (tile >> 3) * 16;
    const int w0 = (tile & 7) * 16;
    const int ty = tid >> 4;            // 0..15
    const int tx = tid & 15;            // 0..15

    // preload weights
    for (int i = tid; i < 4096; i += 256) {
        int o = i >> 8, c = i & 255;
        wT[c][o] = offw[i];             // offw row-major [o][c]
    }
    for (int i = tid; i < 2304; i += 256) {
        wd[i / 9][i % 9] = dww[i];
    }
    if (tid < 16) bsh[tid] = offb[tid];

    const float* xb = x + (size_t)b * CHW_;
    float acc[16] = {};

    for (int c0 = 0; c0 < 256; c0 += 4) {
        __syncthreads();                // xt reuse + (first iter) weight visibility
        // cooperative load of 4 x 18x18 halo tiles (zero-padded at borders)
        for (int i = tid; i < 1296; i += 256) {
            int cc = i / 324;
            int r = i - cc * 324;
            int row = r / 18;
            int col = r - row * 18;
            int hh = h0 + row - 1;
            int ww = w0 + col - 1;
            float v = 0.f;
            if (hh >= 0 && hh < H_ && ww >= 0 && ww < W_)
                v = xb[(size_t)(c0 + cc) * HW_ + hh * W_ + ww];
            xt[cc][row][col] = v;
        }
        __syncthreads();
#pragma unroll
        for (int cc = 0; cc < 4; ++cc) {
            int c = c0 + cc;
            float s = 0.f;
#pragma unroll
            for (int ky = 0; ky < 3; ++ky)
#pragma unroll
                for (int kx = 0; kx < 3; ++kx)
                    s += xt[cc][ty + ky][tx + kx] * wd[c][ky * 3 + kx];
#pragma unroll
            for (int o = 0; o < 16; ++o) acc[o] += s * wT[c][o];
        }
    }

    int pix = (h0 + ty) * W_ + (w0 + tx);
    float* ob = offout + (size_t)b * 16 * HW_ + pix;
#pragma unroll
    for (int o = 0; o < 16; ++o)
        ob[(size_t)o * HW_] = tanhf(acc[o] + bsh[o]) * 0.5f;
}

// ---------------- fp32 GEMM: Y[b] (256 x HW) = Wmat (256x256) * X[b] (256 x HW) ----------------
// 128x128 tile, BK=8, 256 threads, 8x8 per thread.
#define BM 128
#define BN 128
#define BK 8
__global__ __launch_bounds__(256) void gemm_kernel(const float* __restrict__ Wmat,
                                                   const float* __restrict__ Xin,
                                                   float* __restrict__ Yout) {
    __shared__ float As[BK][BM];
    __shared__ float Bs[BK][BN];
    const int tid = threadIdx.x;
    const int b = blockIdx.z;
    const int m0 = blockIdx.y * BM;
    const int n0 = blockIdx.x * BN;
    const float* Xb = Xin + (size_t)b * CHW_;
    float* Yb = Yout + (size_t)b * CHW_;
    const int tx = tid & 15;   // n-group
    const int ty = tid >> 4;   // m-group
    const int a_m = tid >> 1;          // 0..127
    const int a_k = (tid & 1) * 4;     // 0 or 4
    const int b_k = tid >> 5;          // 0..7
    const int b_n = (tid & 31) * 4;    // 0..124
    float acc[8][8] = {};
    for (int k0 = 0; k0 < 256; k0 += BK) {
        float4 av = *(const float4*)&Wmat[(m0 + a_m) * 256 + k0 + a_k];
        float4 bv = *(const float4*)&Xb[(size_t)(k0 + b_k) * HW_ + n0 + b_n];
        __syncthreads();   // previous tile fully consumed
        As[a_k + 0][a_m] = av.x;
        As[a_k + 1][a_m] = av.y;
        As[a_k + 2][a_m] = av.z;
        As[a_k + 3][a_m] = av.w;
        *(float4*)&Bs[b_k][b_n] = bv;
        __syncthreads();
#pragma unroll
        for (int kk = 0; kk < BK; ++kk) {
            float4 a0 = *(const float4*)&As[kk][ty * 8];
            float4 a1 = *(const float4*)&As[kk][ty * 8 + 4];
            float4 b0 = *(const float4*)&Bs[kk][tx * 8];
            float4 b1 = *(const float4*)&Bs[kk][tx * 8 + 4];
            float a_[8] = {a0.x, a0.y, a0.z, a0.w, a1.x, a1.y, a1.z, a1.w};
            float b_[8] = {b0.x, b0.y, b0.z, b0.w, b1.x, b1.y, b1.z, b1.w};
#pragma unroll
            for (int i = 0; i < 8; ++i)
#pragma unroll
                for (int j = 0; j < 8; ++j) acc[i][j] += a_[i] * b_[j];
        }
    }
#pragma unroll
    for (int i = 0; i < 8; ++i) {
        int m = m0 + ty * 8 + i;
        float* yrow = Yb + (size_t)m * HW_ + n0 + tx * 8;
        *(float4*)&yrow[0] = make_float4(acc[i][0], acc[i][1], acc[i][2], acc[i][3]);
        *(float4*)&yrow[4] = make_float4(acc[i][4], acc[i][5], acc[i][6], acc[i][7]);
    }
}

// ---------------- bilinear deformable sampling ----------------
__global__ __launch_bounds__(256) void sample_kernel(const float* __restrict__ V,
                                                     const float* __restrict__ off,
                                                     float* __restrict__ out) {
    int idx = blockIdx.x * 256 + threadIdx.x;
    int p = idx & (HW_ - 1);
    int c = (idx >> 14) & 255;
    int b = idx >> 22;
    int head = c >> 5;
    int h = p >> 7, w = p & 127;
    const float* ob = off + (size_t)(b * 16 + head * 2) * HW_ + p;
    float dy = ob[0];
    float dx = ob[HW_];
    float gy = h * (2.0f / 127.0f) - 1.0f;
    float gx = w * (2.0f / 127.0f) - 1.0f;
    float sx = fminf(fmaxf(gx + dx, -1.0f), 1.0f);
    float sy = fminf(fmaxf(gy + dy, -1.0f), 1.0f);
    float ix = (sx + 1.0f) * 0.5f * 127.0f;
    float iy = (sy + 1.0f) * 0.5f * 127.0f;
    float x0f = floorf(ix), y0f = floorf(iy);
    float wx = ix - x0f, wy = iy - y0f;
    int x0 = min(max((int)x0f, 0), 127);
    int x1 = min((int)x0f + 1, 127);
    int y0 = min(max((int)y0f, 0), 127);
    int y1 = min((int)y0f + 1, 127);
    const float* Vb = V + ((size_t)b * C_ + c) * HW_;
    float v00 = Vb[y0 * W_ + x0];
    float v01 = Vb[y0 * W_ + x1];
    float v10 = Vb[y1 * W_ + x0];
    float v11 = Vb[y1 * W_ + x1];
    float s = v00 * (1.f - wx) * (1.f - wy) + v01 * wx * (1.f - wy) +
              v10 * (1.f - wx) * wy + v11 * wx * wy;
    out[idx] = s;
}

// ---------------- group sum / sumsq (per (b, head), 524288 elems each) ----------------
__global__ __launch_bounds__(256) void reduce_kernel(const float* __restrict__ g,
                                                     float* __restrict__ stats) {
    int blk = blockIdx.x;   // 64 groups * 16 sub-blocks
    int grp = blk >> 4;
    int sub = blk & 15;
    const float* base = g + (size_t)grp * (HD_ * HW_) + (size_t)sub * 32768;
    float s1 = 0.f, s2 = 0.f;
    for (int i = threadIdx.x * 4; i < 32768; i += 1024) {
        float4 v = *(const float4*)&base[i];
        s1 += v.x + v.y + v.z + v.w;
        s2 += v.x * v.x + v.y * v.y + v.z * v.z + v.w * v.w;
    }
#pragma unroll
    for (int o = 32; o; o >>= 1) {
        s1 += __shfl_down(s1, o);
        s2 += __shfl_down(s2, o);
    }
    __shared__ float ls1[4], ls2[4];
    int wave = threadIdx.x >> 6, lane = threadIdx.x & 63;
    if (lane == 0) { ls1[wave] = s1; ls2[wave] = s2; }
    __syncthreads();
    if (threadIdx.x == 0) {
        atomicAdd(&stats[grp * 2 + 0], ls1[0] + ls1[1] + ls1[2] + ls1[3]);
        atomicAdd(&stats[grp * 2 + 1], ls2[0] + ls2[1] + ls2[2] + ls2[3]);
    }
}

// ---------------- normalize + affine + residual ----------------
__global__ __launch_bounds__(256) void final_kernel(const float* __restrict__ x,
                                                    const float* __restrict__ stats,
                                                    const float* __restrict__ gamma,
                                                    const float* __restrict__ beta,
                                                    float* __restrict__ out) {
    int idx = blockIdx.x * 256 + threadIdx.x;
    int c = (idx >> 14) & 255;
    int b = idx >> 22;
    int grp = b * NH_ + (c >> 5);
    const float invN = 1.0f / (float)(HD_ * HW_);
    float mu = stats[grp * 2 + 0] * invN;
    float var = stats[grp * 2 + 1] * invN - mu * mu;
    float r = rsqrtf(var + 1e-5f);
    float v = out[idx];
    out[idx] = x[idx] + (v - mu) * r * gamma[c] + beta[c];
}

extern "C" void kernel_launch(void* const* d_in, const int* in_sizes, int n_in,
                              void* d_out, int out_size, void* d_ws, size_t ws_size,
                              hipStream_t stream) {
    const float* x     = (const float*)d_in[0];
    const float* dww   = (const float*)d_in[1];
    const float* offw  = (const float*)d_in[2];
    const float* offb  = (const float*)d_in[3];
    const float* vw    = (const float*)d_in[4];
    const float* ow    = (const float*)d_in[5];
    const float* gamma = (const float*)d_in[6];
    const float* beta  = (const float*)d_in[7];
    float* out = (float*)d_out;
    float* ws = (float*)d_ws;

    float* off_buf = ws;                 // 2,097,152 floats (8.4 MB)
    float* stats   = ws + 2097152;       // 128 floats
    float* slot1   = ws + 4194304;       // 33,554,432 floats (sampled)

    // 1+2. fused depthwise conv + offset projection -> off_buf
    fused_offset_kernel<<<512, 256, 0, stream>>>(x, dww, offw, offb, off_buf);
    // 3. V projection -> d_out (staging)
    gemm_kernel<<<dim3(HW_ / BN, C_ / BM, B_), 256, 0, stream>>>(vw, x, out);
    // 4. deformable bilinear sampling -> slot1
    sample_kernel<<<NTOT / 256, 256, 0, stream>>>(out, off_buf, slot1);
    // 5. O projection -> d_out (V dead)
    gemm_kernel<<<dim3(HW_ / BN, C_ / BM, B_), 256, 0, stream>>>(ow, slot1, out);
    // 6. group stats
    hipMemsetAsync(stats, 0, 128 * sizeof(float), stream);
    reduce_kernel<<<1024, 256, 0, stream>>>(out, stats);
    // 7. normalize + residual -> d_out
    final_kernel<<<NTOT / 256, 256, 0, stream>>>(x, stats, gamma, beta, out);
}

// Round 3
// 809.930 us; speedup vs baseline: 1.4092x; 1.4092x over previous
//
#include <hip/hip_runtime.h>
#include <hip/hip_bf16.h>

#define B_ 8
#define C_ 256
#define H_ 128
#define W_ 128
#define HW_ 16384
#define CHW_ (C_ * HW_)
#define NH_ 8
#define HD_ 32
#define NTOT (B_ * CHW_)   // 33,554,432

typedef short short8 __attribute__((ext_vector_type(8)));
typedef float f32x4 __attribute__((ext_vector_type(4)));

// ---------------- weight fp32 -> bf16 convert ----------------
__global__ __launch_bounds__(256) void wconv_kernel(const float* __restrict__ vw,
                                                    const float* __restrict__ ow,
                                                    __hip_bfloat16* __restrict__ wvb,
                                                    __hip_bfloat16* __restrict__ wob) {
    int i = blockIdx.x * 256 + threadIdx.x;   // 65536
    wvb[i] = __float2bfloat16(vw[i]);
    wob[i] = __float2bfloat16(ow[i]);
}

// ---------------- x [b][c][p] fp32 -> xT [b][p][c] bf16 (LDS-tiled transpose) ----------------
__global__ __launch_bounds__(256) void xt_kernel(const float* __restrict__ x,
                                                 __hip_bfloat16* __restrict__ xT) {
    __shared__ float tile[64][68];
    int t = threadIdx.x;
    int p0 = blockIdx.x * 64, c0 = blockIdx.y * 64, b = blockIdx.z;
    const float* xb = x + ((size_t)b * C_ + c0) * HW_ + p0;
#pragma unroll
    for (int l = 0; l < 4; ++l) {
        int idx = t + 256 * l;
        int row = idx >> 4, cf = idx & 15;
        float4 v = *(const float4*)&xb[(size_t)row * HW_ + cf * 4];
        *(float4*)&tile[row][cf * 4] = v;
    }
    __syncthreads();
    __hip_bfloat16* op = xT + ((size_t)b * HW_ + p0) * C_ + c0;
#pragma unroll
    for (int l = 0; l < 2; ++l) {
        int idx = t + 256 * l;
        int p = idx & 63, oct = idx >> 6;    // oct 0..7
        __hip_bfloat16 arr[8];
#pragma unroll
        for (int j = 0; j < 8; ++j) arr[j] = __float2bfloat16(tile[oct * 8 + j][p]);
        *(int4*)(op + (size_t)p * C_ + oct * 8) = *(int4*)arr;
    }
}

// ---------------- FUSED dwconv3x3 + partial offset projection ----------------
// grid (16 row-tiles, 8 cgroups, 8 b); block 256. Tile = 128w x 8h, cgroup = 32 ch.
__global__ __launch_bounds__(256) void fused_offset_kernel(const float* __restrict__ x,
                                                           const float* __restrict__ dww,
                                                           const float* __restrict__ offw,
                                                           float* __restrict__ partials) {
    __shared__ float xt[4][10][136];   // 4 ch, 10 halo rows, col+4 shift, pad
    __shared__ float wT[32][16];
    __shared__ float wd[32][9];
    int t = threadIdx.x;
    int rt = blockIdx.x, cg = blockIdx.y, b = blockIdx.z;
    int h0 = rt * 8, c0 = cg * 32;
    for (int i = t; i < 512; i += 256) { int o = i >> 5, c = i & 31; wT[c][o] = offw[o * 256 + c0 + c]; }
    for (int i = t; i < 288; i += 256) { wd[i / 9][i % 9] = dww[(c0 + i / 9) * 9 + i % 9]; }
    const float* xb = x + ((size_t)b * C_ + c0) * HW_;
    int col = t & 127;
    int sb = (t >> 7) * 4;             // row-strip base 0 or 4
    float acc[4][16] = {};
    for (int cc0 = 0; cc0 < 32; cc0 += 4) {
        __syncthreads();
#pragma unroll
        for (int l = 0; l < 5; ++l) {
            int idx = t + 256 * l;             // 0..1279
            int pr = idx >> 5, c4 = idx & 31;
            int cc = pr / 10, r = pr - cc * 10;
            int gh = h0 - 1 + r;
            float4 v = make_float4(0.f, 0.f, 0.f, 0.f);
            if (gh >= 0 && gh < H_)
                v = *(const float4*)&xb[(size_t)(cc0 + cc) * HW_ + gh * W_ + c4 * 4];
            *(float4*)&xt[cc][r][4 + c4 * 4] = v;
        }
        if (t < 80) { int pr = t >> 1, side = t & 1; xt[pr / 10][pr % 10][side ? 132 : 3] = 0.f; }
        __syncthreads();
#pragma unroll
        for (int cc = 0; cc < 4; ++cc) {
            float win[6][3];
#pragma unroll
            for (int rr = 0; rr < 6; ++rr)
#pragma unroll
                for (int kk = 0; kk < 3; ++kk)
                    win[rr][kk] = xt[cc][sb + rr][col + 3 + kk];
            float w9[9];
#pragma unroll
            for (int k9 = 0; k9 < 9; ++k9) w9[k9] = wd[cc0 + cc][k9];
#pragma unroll
            for (int j = 0; j < 4; ++j) {
                float s = 0.f;
#pragma unroll
                for (int ky = 0; ky < 3; ++ky)
#pragma unroll
                    for (int kx = 0; kx < 3; ++kx)
                        s += win[j + ky][kx] * w9[ky * 3 + kx];
#pragma unroll
                for (int o = 0; o < 16; ++o) acc[j][o] += s * wT[cc0 + cc][o];
            }
        }
    }
    float* pb = partials + (size_t)(cg * 8 + b) * 16 * HW_;
#pragma unroll
    for (int o = 0; o < 16; ++o)
#pragma unroll
        for (int j = 0; j < 4; ++j)
            pb[(size_t)o * HW_ + (h0 + sb + j) * W_ + col] = acc[j][o];
}

// ---------------- sum 8 partials + bias + tanh ----------------
__global__ __launch_bounds__(256) void offreduce_kernel(const float* __restrict__ partials,
                                                        const float* __restrict__ offb,
                                                        float* __restrict__ off_buf) {
    int i = blockIdx.x * 256 + threadIdx.x;     // 0..2097151 over [b][o][p]
    float s = 0.f;
#pragma unroll
    for (int cg = 0; cg < 8; ++cg) s += partials[(size_t)cg * 2097152 + i];
    int o = (i >> 14) & 15;
    off_buf[i] = tanhf(s + offb[o]) * 0.5f;
}

// ---------------- bf16 MFMA GEMM: Y[b](256 x HW) = W(256x256) * X[b], X given as X^T [p][c] ----------------
// block 256 thr (4 waves), tile 128m x 128n, BK=32, 8 K-steps.
__global__ __launch_bounds__(256) void mfma_gemm(const __hip_bfloat16* __restrict__ Wb,
                                                 const __hip_bfloat16* __restrict__ Xt,
                                                 float* __restrict__ Y) {
    __shared__ __align__(16) short As[128][40];   // [m][k] + 8-short pad (80 B rows)
    __shared__ __align__(16) short Bs[128][40];   // [n][k] + pad
    int t = threadIdx.x;
    int wave = t >> 6, lane = t & 63;
    int quad = lane >> 4, l16 = lane & 15;
    int b = blockIdx.z;
    int n0 = blockIdx.x * 128, m0 = blockIdx.y * 128;
    const short* Wp = (const short*)Wb + (size_t)m0 * 256;
    const short* Xp = (const short*)Xt + ((size_t)b * HW_ + n0) * 256;
    int sr = t >> 2, sq = t & 3;      // staging: row 0..63 (+64), k-oct 0..3
    f32x4 acc[2][8];
#pragma unroll
    for (int mt = 0; mt < 2; ++mt)
#pragma unroll
        for (int nt = 0; nt < 8; ++nt) acc[mt][nt] = (f32x4){0.f, 0.f, 0.f, 0.f};
    for (int k0 = 0; k0 < 256; k0 += 32) {
        int4 a0 = *(const int4*)(Wp + (size_t)sr * 256 + k0 + sq * 8);
        int4 a1 = *(const int4*)(Wp + (size_t)(sr + 64) * 256 + k0 + sq * 8);
        int4 b0 = *(const int4*)(Xp + (size_t)sr * 256 + k0 + sq * 8);
        int4 b1 = *(const int4*)(Xp + (size_t)(sr + 64) * 256 + k0 + sq * 8);
        __syncthreads();
        *(int4*)&As[sr][sq * 8] = a0;
        *(int4*)&As[sr + 64][sq * 8] = a1;
        *(int4*)&Bs[sr][sq * 8] = b0;
        *(int4*)&Bs[sr + 64][sq * 8] = b1;
        __syncthreads();
        short8 af[2], bf[8];
#pragma unroll
        for (int mt = 0; mt < 2; ++mt)
            af[mt] = *(const short8*)&As[wave * 32 + mt * 16 + l16][quad * 8];
#pragma unroll
        for (int nt = 0; nt < 8; ++nt)
            bf[nt] = *(const short8*)&Bs[nt * 16 + l16][quad * 8];
#pragma unroll
        for (int mt = 0; mt < 2; ++mt)
#pragma unroll
            for (int nt = 0; nt < 8; ++nt)
                acc[mt][nt] = __builtin_amdgcn_mfma_f32_16x16x32_bf16(af[mt], bf[nt], acc[mt][nt], 0, 0, 0);
    }
    float* Yb = Y + (size_t)b * CHW_;
#pragma unroll
    for (int mt = 0; mt < 2; ++mt)
#pragma unroll
        for (int nt = 0; nt < 8; ++nt)
#pragma unroll
            for (int r = 0; r < 4; ++r) {
                int m = m0 + wave * 32 + mt * 16 + quad * 4 + r;
                int n = n0 + nt * 16 + l16;
                Yb[(size_t)m * HW_ + n] = acc[mt][nt][r];
            }
}

// ---------------- deformable bilinear sampling -> sampledT bf16 [b][p][c] ----------------
// grid (64 p-tiles, 8 heads, 8 b); thread = pixel, loops 32 head channels.
__global__ __launch_bounds__(256) void sample_kernel(const float* __restrict__ V,
                                                     const float* __restrict__ off,
                                                     __hip_bfloat16* __restrict__ sT) {
    int t = threadIdx.x;
    int p = blockIdx.x * 256 + t;
    int head = blockIdx.y, b = blockIdx.z;
    int h = p >> 7, w = p & 127;
    const float* ob = off + ((size_t)b * 16 + head * 2) * HW_ + p;
    float dy = ob[0], dx = ob[HW_];
    float gy = h * (2.0f / 127.0f) - 1.0f;
    float gx = w * (2.0f / 127.0f) - 1.0f;
    float sx = fminf(fmaxf(gx + dx, -1.0f), 1.0f);
    float sy = fminf(fmaxf(gy + dy, -1.0f), 1.0f);
    float ix = (sx + 1.0f) * 0.5f * 127.0f;
    float iy = (sy + 1.0f) * 0.5f * 127.0f;
    float x0f = floorf(ix), y0f = floorf(iy);
    float wx = ix - x0f, wy = iy - y0f;
    int x0 = min(max((int)x0f, 0), 127);
    int x1 = min((int)x0f + 1, 127);
    int y0 = min(max((int)y0f, 0), 127);
    int y1 = min((int)y0f + 1, 127);
    float w00 = (1.f - wx) * (1.f - wy), w01 = wx * (1.f - wy);
    float w10 = (1.f - wx) * wy, w11 = wx * wy;
    int i00 = y0 * W_ + x0, i01 = y0 * W_ + x1;
    int i10 = y1 * W_ + x0, i11 = y1 * W_ + x1;
    const float* Vb = V + ((size_t)b * C_ + head * 32) * HW_;
    __hip_bfloat16* op = sT + ((size_t)b * HW_ + p) * C_ + head * 32;
#pragma unroll
    for (int c8 = 0; c8 < 4; ++c8) {
        __hip_bfloat16 arr[8];
#pragma unroll
        for (int j = 0; j < 8; ++j) {
            const float* Vc = Vb + (size_t)(c8 * 8 + j) * HW_;
            float s = Vc[i00] * w00 + Vc[i01] * w01 + Vc[i10] * w10 + Vc[i11] * w11;
            arr[j] = __float2bfloat16(s);
        }
        *(int4*)(op + c8 * 8) = *(int4*)arr;
    }
}

// ---------------- group sum / sumsq ----------------
__global__ __launch_bounds__(256) void reduce_kernel(const float* __restrict__ g,
                                                     float* __restrict__ stats) {
    int blk = blockIdx.x;
    int grp = blk >> 4;
    int sub = blk & 15;
    const float* base = g + (size_t)grp * (HD_ * HW_) + (size_t)sub * 32768;
    float s1 = 0.f, s2 = 0.f;
    for (int i = threadIdx.x * 4; i < 32768; i += 1024) {
        float4 v = *(const float4*)&base[i];
        s1 += v.x + v.y + v.z + v.w;
        s2 += v.x * v.x + v.y * v.y + v.z * v.z + v.w * v.w;
    }
#pragma unroll
    for (int o = 32; o; o >>= 1) {
        s1 += __shfl_down(s1, o);
        s2 += __shfl_down(s2, o);
    }
    __shared__ float ls1[4], ls2[4];
    int wave = threadIdx.x >> 6, lane = threadIdx.x & 63;
    if (lane == 0) { ls1[wave] = s1; ls2[wave] = s2; }
    __syncthreads();
    if (threadIdx.x == 0) {
        atomicAdd(&stats[grp * 2 + 0], ls1[0] + ls1[1] + ls1[2] + ls1[3]);
        atomicAdd(&stats[grp * 2 + 1], ls2[0] + ls2[1] + ls2[2] + ls2[3]);
    }
}

// ---------------- normalize + affine + residual ----------------
__global__ __launch_bounds__(256) void final_kernel(const float* __restrict__ x,
                                                    const float* __restrict__ stats,
                                                    const float* __restrict__ gamma,
                                                    const float* __restrict__ beta,
                                                    float* __restrict__ out) {
    int idx = blockIdx.x * 256 + threadIdx.x;
    int c = (idx >> 14) & 255;
    int b = idx >> 22;
    int grp = b * NH_ + (c >> 5);
    const float invN = 1.0f / (float)(HD_ * HW_);
    float mu = stats[grp * 2 + 0] * invN;
    float var = stats[grp * 2 + 1] * invN - mu * mu;
    float r = rsqrtf(var + 1e-5f);
    float v = out[idx];
    out[idx] = x[idx] + (v - mu) * r * gamma[c] + beta[c];
}

extern "C" void kernel_launch(void* const* d_in, const int* in_sizes, int n_in,
                              void* d_out, int out_size, void* d_ws, size_t ws_size,
                              hipStream_t stream) {
    const float* x     = (const float*)d_in[0];
    const float* dww   = (const float*)d_in[1];
    const float* offw  = (const float*)d_in[2];
    const float* offb  = (const float*)d_in[3];
    const float* vw    = (const float*)d_in[4];
    const float* ow    = (const float*)d_in[5];
    const float* gamma = (const float*)d_in[6];
    const float* beta  = (const float*)d_in[7];
    float* out = (float*)d_out;
    float* ws_f = (float*)d_ws;

    // ws layout (floats): total ~35.7M floats = 143 MB
    float* partials = ws_f;                                   // 16,777,216 f
    float* off_buf  = ws_f + 16777216;                        //  2,097,152 f
    float* stats    = ws_f + 18874368;                        //        256 f
    __hip_bfloat16* wvb = (__hip_bfloat16*)(ws_f + 18874624); //  65,536 bf16
    __hip_bfloat16* wob = wvb + 65536;                        //  65,536 bf16
    __hip_bfloat16* xT  = (__hip_bfloat16*)(ws_f + 18940160); //  33,554,432 bf16
    __hip_bfloat16* sT  = (__hip_bfloat16*)partials;          //  alias region A (partials dead)

    // 1. weight converts + x transpose to bf16
    wconv_kernel<<<256, 256, 0, stream>>>(vw, ow, wvb, wob);
    xt_kernel<<<dim3(256, 4, 8), 256, 0, stream>>>(x, xT);
    // 2. fused dwconv + partial offset proj
    fused_offset_kernel<<<dim3(16, 8, 8), 256, 0, stream>>>(x, dww, offw, partials);
    offreduce_kernel<<<8192, 256, 0, stream>>>(partials, offb, off_buf);
    // 3. V = vw * x (bf16 MFMA) -> d_out fp32 staging
    mfma_gemm<<<dim3(128, 2, 8), 256, 0, stream>>>(wvb, xT, out);
    // 4. deformable sampling -> sT bf16 [p][c]
    sample_kernel<<<dim3(64, 8, 8), 256, 0, stream>>>(out, off_buf, sT);
    // 5. out = ow * sampled (bf16 MFMA) -> d_out fp32
    mfma_gemm<<<dim3(128, 2, 8), 256, 0, stream>>>(wob, sT, out);
    // 6. group stats + normalize + residual
    hipMemsetAsync(stats, 0, 128 * sizeof(float), stream);
    reduce_kernel<<<1024, 256, 0, stream>>>(out, stats);
    final_kernel<<<NTOT / 256, 256, 0, stream>>>(x, stats, gamma, beta, out);
}